// Round 1
// baseline (216.898 us; speedup 1.0000x reference)
//
#include <hip/hip_runtime.h>

// MSDeformAttn forward, MI355X. Round 8: LDS-resident levels 2+3.
// Evidence R0-R7: main kernel is bound by random 128B-line gather rate
// (~0.215 lines/cyc/CU, consistent with ~64 outstanding misses x ~220cy L2
// latency). Fix: serve l2 (60.8KB) + l3 (15.8KB) gathers from LDS (separate
// pipe, ~3x cheaper per row, overlaps VMEM). Persistent blocks (1/CU,
// 16/slice, ~20 query-chunks each) amortize the one-time LDS staging.
// VMEM lines/query·slice: 36 -> 20. Repack now l0+l1 only (v16 slice
// footprint 1.459MB -> 2.92MB/XCD for 2 slices, better L2 headroom).
#define NLV  4
#define CCH  32
#define HD   8
#define QTOT 19947
#define LTOT 19947
#define BB   2

typedef float        f32x4 __attribute__((ext_vector_type(4)));
typedef float        f32x2 __attribute__((ext_vector_type(2)));
typedef _Float16     f16x8 __attribute__((ext_vector_type(8)));
typedef unsigned int u32;
typedef u32          u32x2 __attribute__((ext_vector_type(2)));

// ---- v16 layout (per slice = (b,h)), byte offsets; l0+l1 only ----
// l0: padded rows: 100 x 152 texels x 64B            @ 0        (972,800)
// l1 c0: 50 x 38 pairs x 128B @ 972,800 | c1: 50x38 @ 1,216,000 (ends 1,459,200)
#define SLICE_BYTES 1459200
#define WS_NEED     (16UL * SLICE_BYTES)
#define CHUNKS_PER_SLICE 91200
#define TOTAL_CHUNKS (16 * CHUNKS_PER_SLICE)

// ---------------- pre-pass: value fp32 -> repacked fp16 (l0, l1) --------
__global__ __launch_bounds__(256) void repack_f16(
    const float* __restrict__ value, _Float16* __restrict__ v16)
{
    const int id = blockIdx.x * 256 + (int)threadIdx.x;
    if (id >= TOTAL_CHUNKS) return;
    const int slice = id / CHUNKS_PER_SLICE;
    const int r     = id - slice * CHUNKS_PER_SLICE;
    const int b = slice >> 3, h = slice & 7;

    int x, y, k, W, S;
    if (r < 60800) {                 // l0 plain, rows of 152 texels (4 chunks ea)
        y = r / 608; const int rr = r - y * 608;
        x = (rr >> 2) - 1; k = rr & 3; W = 150; S = 0;
    } else if (r < 76000) {          // l1 copy0, cN=38
        const int i = r - 60800; y = i / 304; const int rr = i - y * 304;
        x = ((rr >> 3) << 1) + ((rr >> 2) & 1);     k = rr & 3; W = 75; S = 15000;
    } else {                         // l1 copy1
        const int i = r - 76000; y = i / 304; const int rr = i - y * 304;
        x = ((rr >> 3) << 1) + ((rr >> 2) & 1) - 1; k = rr & 3; W = 75; S = 15000;
    }

    f16x8 o = {(_Float16)0.f, (_Float16)0.f, (_Float16)0.f, (_Float16)0.f,
               (_Float16)0.f, (_Float16)0.f, (_Float16)0.f, (_Float16)0.f};
    if (x >= 0 && x < W) {
        const float* src = value +
            (((size_t)(b * LTOT + S + y * W + x) * HD + h) * CCH + k * 8);
        const f32x4 a = *(const f32x4*)src;
        const f32x4 c = *(const f32x4*)(src + 4);
        o[0] = (_Float16)a.x; o[1] = (_Float16)a.y;
        o[2] = (_Float16)a.z; o[3] = (_Float16)a.w;
        o[4] = (_Float16)c.x; o[5] = (_Float16)c.y;
        o[6] = (_Float16)c.z; o[7] = (_Float16)c.w;
    }
    *(f16x8*)((char*)v16 + (size_t)id * 16) = o;
}

// ---------------- main kernel ----------------
#define GPB     64                    // queries per chunk (8-lane groups, 512 thr)
#define JOBS    (GPB * 16)            // 1024
#define QBLOCKS 312                   // ceil(19947/64)
#define PARTS   16                    // persistent blocks per slice (grid=256)

// dynamic LDS layout (bytes)
#define SW_OFF  8192                  // s_of: [0,8192) = 1024 x u32x2
#define A2      24576                 // s_w : [8192,24576) = 1024 x f32x4
#define NTEX2   950                   // l2: 25x38 texels, plain, +1 pad texel
#define A3      85440                 // A2 + 950*64 + 64
#define NTEX3   247                   // l3: 13x19 texels, plain, +1 pad texel
#define SMEM_TOTAL 101312             // A3 + 247*64 + 64
#define NTEX    (NTEX2 + NTEX3)

__device__ __forceinline__ unsigned jslot(int gl, int s) {
    return (unsigned)(gl * 16 + (s ^ (gl & 7)));   // bijective; conflict-free
}

__global__ __launch_bounds__(512, 2) void msda_fwd_v2(
    const _Float16* __restrict__ v16,   // repacked l0+l1
    const float* __restrict__ value,    // original fp32 (for l2/l3 staging)
    const float* __restrict__ loc,
    const float* __restrict__ attw,
    float* __restrict__ out)
{
    extern __shared__ __align__(16) char smem[];

    const int Hs[NLV] = {100, 50, 25, 13};
    const int Ws[NLV] = {150, 75, 38, 19};

    const int slice = blockIdx.x & 15;   // pins (b,h) to XCD (L2 residency)
    const int part  = blockIdx.x >> 4;   // 0..15 persistent partition
    const int b = slice >> 3;
    const int h = slice & 7;
    const int t = (int)threadIdx.x;

    // ---- one-time stage: l2+l3 fp32 -> fp16 into LDS (plain layout) ----
    {
        const f16x8 z = {(_Float16)0.f, (_Float16)0.f, (_Float16)0.f, (_Float16)0.f,
                         (_Float16)0.f, (_Float16)0.f, (_Float16)0.f, (_Float16)0.f};
        for (int task = t; task < NTEX * 4 + 8; task += 512) {
            if (task < NTEX * 4) {
                const int ti = task >> 2, p = task & 3;   // 4 lanes per texel
                int src_lp, lds;
                if (ti < NTEX2) { src_lp = 18750 + ti;           lds = A2 + ti * 64; }
                else            { src_lp = 19700 + (ti - NTEX2); lds = A3 + (ti - NTEX2) * 64; }
                const float* src = value +
                    (((size_t)(b * LTOT + src_lp)) * HD + h) * CCH + p * 8;
                const f32x4 a = *(const f32x4*)src;
                const f32x4 c = *(const f32x4*)(src + 4);
                f16x8 o;
                o[0] = (_Float16)a.x; o[1] = (_Float16)a.y;
                o[2] = (_Float16)a.z; o[3] = (_Float16)a.w;
                o[4] = (_Float16)c.x; o[5] = (_Float16)c.y;
                o[6] = (_Float16)c.z; o[7] = (_Float16)c.w;
                *(f16x8*)(smem + lds + p * 16) = o;
            } else {
                // zero the 1-texel pads (overrun target for x0==W-1, y==H-1)
                const int pi = task - NTEX * 4;   // 0..7
                const int lds = (pi < 4) ? (A2 + NTEX2 * 64 + pi * 16)
                                         : (A3 + NTEX3 * 64 + (pi - 4) * 16);
                *(f16x8*)(smem + lds) = z;
            }
        }
    }
    // first __syncthreads (inside loop, after phase 1) covers staging.

    for (int qb = part; qb < QBLOCKS; qb += PARTS) {

        // ---------------- Phase 1: 2 jobs/thread -> LDS ----------------
#pragma unroll
        for (int jj = 0; jj < 2; ++jj) {
            const int j  = t + jj * 512;
            const int gl = j >> 4;
            const int s  = j & 15;
            const int l  = s >> 2;
            const int q  = qb * GPB + gl;
            const int qc = min(q, QTOT - 1);
            const size_t og = ((size_t)b * QTOT + qc) * HD + h;

            const f32x2 lxy = __builtin_nontemporal_load((const f32x2*)loc + og * 16 + s);
            float wa = __builtin_nontemporal_load(attw + og * 16 + s);
            if (q >= QTOT) wa = 0.f;

            const int H = Hs[l], W = Ws[l];
            const float x = lxy.x * (float)W - 0.5f;
            const float y = lxy.y * (float)H - 0.5f;
            const float x0f = floorf(x), y0f = floorf(y);
            const float dx = x - x0f,  dy = y - y0f;
            const int x0 = (int)x0f,   y0 = (int)y0f;  // x0 in [-1,W-1], y0 in [-1,H-1]

            // row weights: OOB rows zeroed (row clamp reuses real data)
            const float r0w = ((y0 >= 0) ? (1.f - dy) : 0.f) * wa;
            const float r1w = ((y0 + 1 < H) ? dy : 0.f) * wa;
            f32x4 w;
            w.x = r0w * (1.f - dx);  w.y = r0w * dx;
            w.z = r1w * (1.f - dx);  w.w = r1w * dx;

            const int cy0 = max(y0, 0);
            const int cy1 = min(y0 + 1, H - 1);

            u32 off0, off1;
            if (l == 0) {                      // VMEM: padded rows (pads hold 0)
                const u32 col = (u32)(x0 + 1);
                off0 = ((u32)cy0 * 152u + col) * 64u;
                off1 = ((u32)cy1 * 152u + col) * 64u;
            } else if (l == 1) {               // VMEM: dual x-pair copies
                const int copy = x0 & 1;       // (-1)&1 == 1
                const u32 p  = (u32)((x0 + copy) >> 1);
                const u32 lo = copy ? 1216000u : 972800u;
                off0 = lo + ((u32)cy0 * 38u + p) * 128u;
                off1 = lo + ((u32)cy1 * 38u + p) * 128u;
            } else {                           // LDS: plain layout, no pads ->
                // explicit x edge handling (exactly equivalent to pad scheme):
                if (x0 < 0)     { w.x = w.y; w.z = w.w; w.y = 0.f; w.w = 0.f; }
                if (x0 >= W - 1){ w.y = 0.f; w.w = 0.f; }   // x0+1 OOB
                const u32 xb   = (u32)max(x0, 0);
                const u32 base = (l == 2) ? (u32)A2 : (u32)A3;
                off0 = base + ((u32)cy0 * (u32)W + xb) * 64u;
                off1 = base + ((u32)cy1 * (u32)W + xb) * 64u;
            }

            const unsigned sl = jslot(gl, s);
            u32x2 of; of.x = off0; of.y = off1;
            *(u32x2*)(smem + sl * 8) = of;
            *(f32x4*)(smem + SW_OFF + sl * 16) = w;
        }

        __syncthreads();

        // -------- Phase 2: row-pair gathers (VMEM l0/l1, LDS l2/l3) --------
        {
            const int gl   = t >> 3;             // 0..63
            const int lane = t & 7;              // lanes 0-3 left texel, 4-7 right
            const int lh   = (t >> 2) & 1;
            const int q    = qb * GPB + gl;
            const char* vb = (const char*)v16 + (size_t)slice * SLICE_BYTES + lane * 16;
            const char* lb = smem + lane * 16;

            float acc[8] = {0.f, 0.f, 0.f, 0.f, 0.f, 0.f, 0.f, 0.f};
#pragma unroll
            for (int s = 0; s < 16; ++s) {
                const unsigned sl = jslot(gl, s);
                const u32x2 of = *(const u32x2*)(smem + sl * 8);
                const f32x4 w  = *(const f32x4*)(smem + SW_OFF + sl * 16);
                f16x8 g0, g1;
                if (s < 8) {                     // l0,l1: global (L2) gathers
                    g0 = *(const f16x8*)(vb + of.x);
                    g1 = *(const f16x8*)(vb + of.y);
                } else {                         // l2,l3: LDS gathers
                    g0 = *(const f16x8*)(lb + of.x);
                    g1 = *(const f16x8*)(lb + of.y);
                }
                const float wr0 = lh ? w.y : w.x;
                const float wr1 = lh ? w.w : w.z;
#pragma unroll
                for (int c = 0; c < 8; ++c) {
                    acc[c] += (float)g0[c] * wr0;
                    acc[c] += (float)g1[c] * wr1;
                }
            }

            // combine left/right texel halves (lanes l and l^4: same channels)
#pragma unroll
            for (int c = 0; c < 8; ++c)
                acc[c] += __shfl_xor(acc[c], 4, 64);

            if (q < QTOT) {
                const size_t og = ((size_t)b * QTOT + q) * HD + h;
                f32x4 v;
                v.x = lh ? acc[4] : acc[0];
                v.y = lh ? acc[5] : acc[1];
                v.z = lh ? acc[6] : acc[2];
                v.w = lh ? acc[7] : acc[3];
                __builtin_nontemporal_store(v, (f32x4*)out + og * 8 + (t & 3) * 2 + lh);
            }
        }
        __syncthreads();
    }
}

// ---------------- fallback: fp32 gathers, no workspace/LDS opt-in --------
#define FGPB 32
#define FJOBS (FGPB * 16)
__device__ __forceinline__ unsigned fjslot(int gl, int s) {
    return (unsigned)((gl * 16 + (s ^ (gl & 7))) * 4);
}
__global__ __launch_bounds__(256) void msda_fwd_f32(
    const float* __restrict__ value,
    const float* __restrict__ loc,
    const float* __restrict__ attw,
    float* __restrict__ out)
{
    __shared__ __align__(16) u32   s_ofs[FJOBS * 4];
    __shared__ __align__(16) float s_wts[FJOBS * 4];
    const int Hs[NLV] = {100, 50, 25, 13};
    const int Ws[NLV] = {150, 75, 38, 19};
    const int Ss[NLV] = {0, 15000, 18750, 19700};
    const int slice = blockIdx.x & 15;
    const int blk   = blockIdx.x >> 4;
    const int b = slice >> 3, h = slice & 7;
    const int t = (int)threadIdx.x;
#pragma unroll
    for (int jj = 0; jj < 2; ++jj) {
        const int j  = t + jj * 256;
        const int gl = j >> 4, s = j & 15, l = s >> 2;
        const int q  = blk * FGPB + gl;
        const int qc = min(q, QTOT - 1);
        const size_t og = ((size_t)b * QTOT + qc) * HD + h;
        const f32x2 lxy = __builtin_nontemporal_load((const f32x2*)loc + og * 16 + s);
        float wa = __builtin_nontemporal_load(attw + og * 16 + s);
        if (q >= QTOT) wa = 0.f;
        const int H = Hs[l], W = Ws[l];
        const float x = lxy.x * (float)W - 0.5f;
        const float y = lxy.y * (float)H - 0.5f;
        const float x0f = floorf(x), y0f = floorf(y);
        const float dx = x - x0f, dy = y - y0f;
        const int x0 = (int)x0f, y0 = (int)y0f, x1 = x0 + 1, y1 = y0 + 1;
        const bool vx0 = (x0 >= 0) & (x0 < W), vx1 = (x1 >= 0) & (x1 < W);
        const bool vy0 = (y0 >= 0) & (y0 < H), vy1 = (y1 >= 0) & (y1 < H);
        float w00 = (1.f - dy) * (1.f - dx) * wa, w01 = (1.f - dy) * dx * wa;
        float w10 = dy * (1.f - dx) * wa,         w11 = dy * dx * wa;
        w00 = (vy0 & vx0) ? w00 : 0.f; w01 = (vy0 & vx1) ? w01 : 0.f;
        w10 = (vy1 & vx0) ? w10 : 0.f; w11 = (vy1 & vx1) ? w11 : 0.f;
        const int cx0 = min(max(x0, 0), W - 1), cx1 = min(max(x1, 0), W - 1);
        const int cy0 = min(max(y0, 0), H - 1), cy1 = min(max(y1, 0), H - 1);
        const u32 base = (u32)(((b * LTOT + Ss[l]) * HD + h) * CCH) * 4u;
        const u32 r0 = (u32)(cy0 * W), r1 = (u32)(cy1 * W);
        u32 o0 = base + (r0 + (u32)cx0) * (HD * CCH * 4u);
        u32 o1 = base + (r0 + (u32)cx1) * (HD * CCH * 4u);
        u32 o2 = base + (r1 + (u32)cx0) * (HD * CCH * 4u);
        u32 o3 = base + (r1 + (u32)cx1) * (HD * CCH * 4u);
        const unsigned sb = fjslot(gl, s);
        s_ofs[sb + 0] = o0; s_ofs[sb + 1] = o1;
        s_ofs[sb + 2] = o2; s_ofs[sb + 3] = o3;
        f32x4 wts; wts.x = w00; wts.y = w01; wts.z = w10; wts.w = w11;
        *(f32x4*)&s_wts[sb] = wts;
    }
    __syncthreads();
    const int gl = t >> 3, lane = t & 7;
    const int q  = blk * FGPB + gl;
    const char* vb = (const char*)value + lane * 16;
    f32x4 acc = {0.f, 0.f, 0.f, 0.f};
#pragma unroll
    for (int s = 0; s < 16; ++s) {
        const unsigned sb = fjslot(gl, s);
        const f32x4 w = *(const f32x4*)&s_wts[sb];
        acc += (*(const f32x4*)(vb + s_ofs[sb + 0])) * w.x;
        acc += (*(const f32x4*)(vb + s_ofs[sb + 1])) * w.y;
        acc += (*(const f32x4*)(vb + s_ofs[sb + 2])) * w.z;
        acc += (*(const f32x4*)(vb + s_ofs[sb + 3])) * w.w;
    }
    if (q < QTOT) {
        const size_t og = ((size_t)b * QTOT + q) * HD + h;
        __builtin_nontemporal_store(acc, (f32x4*)out + og * 8 + lane);
    }
}

extern "C" void kernel_launch(void* const* d_in, const int* in_sizes, int n_in,
                              void* d_out, int out_size, void* d_ws, size_t ws_size,
                              hipStream_t stream) {
    const float* value = (const float*)d_in[0];
    const float* loc   = (const float*)d_in[3];
    const float* attw  = (const float*)d_in[4];
    float* out = (float*)d_out;

    static int smem_ok = -1;
    if (smem_ok < 0) {
        smem_ok = (hipFuncSetAttribute(
                       reinterpret_cast<const void*>(msda_fwd_v2),
                       hipFuncAttributeMaxDynamicSharedMemorySize,
                       SMEM_TOTAL) == hipSuccess) ? 1 : 0;
    }

    if (ws_size >= WS_NEED && smem_ok == 1) {
        _Float16* v16 = (_Float16*)d_ws;
        repack_f16<<<(TOTAL_CHUNKS + 255) / 256, 256, 0, stream>>>(value, v16);
        msda_fwd_v2<<<PARTS * 16, 512, SMEM_TOTAL, stream>>>(v16, value, loc, attw, out);
    } else {
        msda_fwd_f32<<<624 * 16, 256, 0, stream>>>(value, loc, attw, out);
    }
}

// Round 2
// 207.628 us; speedup vs baseline: 1.0446x; 1.0446x over previous
//
#include <hip/hip_runtime.h>

// MSDeformAttn forward, MI355X. Round 9: deep-MLP gather batching.
// Evidence R7/R8: gather throughput is LATENCY-bound, rate = outstanding
// misses / ~290cy (R7: 21 waves/CU x ~3 in-flight = 0.215 lines/cyc/CU;
// R8: 8 waves x ~3 = 0.094 -- proportional). R8's LDS-staging occupancy
// collapse reverted. Fix here: batch phase-2 gathers 8-at-a-time into
// statically-indexed register arrays (VGPR cap 128 via launch_bounds) so
// each wave keeps ~8 loads in flight -> ~2x outstanding misses per CU.
#define NLV  4
#define CCH  32
#define HD   8
#define QTOT 19947
#define LTOT 19947
#define BB   2

typedef float        f32x4 __attribute__((ext_vector_type(4)));
typedef float        f32x2 __attribute__((ext_vector_type(2)));
typedef _Float16     f16x8 __attribute__((ext_vector_type(8)));
typedef unsigned int u32;
typedef u32          u32x2 __attribute__((ext_vector_type(2)));

// ---- repacked layout (per slice = (b,h)), all offsets in bytes ----
// l0: plain padded rows: 100 rows x 152 texels x 64B   @ 0        (972,800)
// l1 c0: 50 x 38 pairs x 128B  @  972,800   | l1 c1: 50 x 38 @ 1,216,000
// l2 c0: 25 x 19 pairs x 128B  @ 1,459,200  | l2 c1: 25 x 20 @ 1,520,000
// l3 c0: 13 x 10 pairs x 128B  @ 1,584,000  | l3 c1: 13 x 10 @ 1,600,640
#define SLICE_BYTES 1617280
#define WS_NEED     (16UL * SLICE_BYTES)          // 25,876,480
#define CHUNKS_PER_SLICE 101080                   // SLICE_BYTES/16
#define TOTAL_CHUNKS (16 * CHUNKS_PER_SLICE)

// ---------------- pre-pass: value fp32 -> repacked fp16 ----------------
__global__ __launch_bounds__(256) void repack_f16(
    const float* __restrict__ value, _Float16* __restrict__ v16)
{
    const int id = blockIdx.x * 256 + (int)threadIdx.x;
    if (id >= TOTAL_CHUNKS) return;
    const int slice = id / CHUNKS_PER_SLICE;
    const int r     = id - slice * CHUNKS_PER_SLICE;
    const int b = slice >> 3, h = slice & 7;

    int x, y, k, W, S;
    if (r < 60800) {                 // l0 plain, rows of 152 texels (4 chunks ea)
        y = r / 608; const int rr = r - y * 608;
        x = (rr >> 2) - 1; k = rr & 3; W = 150; S = 0;
    } else if (r < 76000) {          // l1 copy0, cN=38
        const int i = r - 60800; y = i / 304; const int rr = i - y * 304;
        x = ((rr >> 3) << 1) + ((rr >> 2) & 1);     k = rr & 3; W = 75; S = 15000;
    } else if (r < 91200) {          // l1 copy1
        const int i = r - 76000; y = i / 304; const int rr = i - y * 304;
        x = ((rr >> 3) << 1) + ((rr >> 2) & 1) - 1; k = rr & 3; W = 75; S = 15000;
    } else if (r < 95000) {          // l2 copy0, cN=19
        const int i = r - 91200; y = i / 152; const int rr = i - y * 152;
        x = ((rr >> 3) << 1) + ((rr >> 2) & 1);     k = rr & 3; W = 38; S = 18750;
    } else if (r < 99000) {          // l2 copy1, cN=20
        const int i = r - 95000; y = i / 160; const int rr = i - y * 160;
        x = ((rr >> 3) << 1) + ((rr >> 2) & 1) - 1; k = rr & 3; W = 38; S = 18750;
    } else if (r < 100040) {         // l3 copy0, cN=10
        const int i = r - 99000; y = i / 80; const int rr = i - y * 80;
        x = ((rr >> 3) << 1) + ((rr >> 2) & 1);     k = rr & 3; W = 19; S = 19700;
    } else {                         // l3 copy1, cN=10
        const int i = r - 100040; y = i / 80; const int rr = i - y * 80;
        x = ((rr >> 3) << 1) + ((rr >> 2) & 1) - 1; k = rr & 3; W = 19; S = 19700;
    }

    f16x8 o = {(_Float16)0.f, (_Float16)0.f, (_Float16)0.f, (_Float16)0.f,
               (_Float16)0.f, (_Float16)0.f, (_Float16)0.f, (_Float16)0.f};
    if (x >= 0 && x < W) {
        const float* src = value +
            (((size_t)(b * LTOT + S + y * W + x) * HD + h) * CCH + k * 8);
        const f32x4 a = *(const f32x4*)src;
        const f32x4 c = *(const f32x4*)(src + 4);
        o[0] = (_Float16)a.x; o[1] = (_Float16)a.y;
        o[2] = (_Float16)a.z; o[3] = (_Float16)a.w;
        o[4] = (_Float16)c.x; o[5] = (_Float16)c.y;
        o[6] = (_Float16)c.z; o[7] = (_Float16)c.w;
    }
    *(f16x8*)((char*)v16 + (size_t)id * 16) = o;
}

// ---------------- main kernel ----------------
#define GPB  32                              // queries per block (8-lane groups)
#define JOBS (GPB * 16)                      // 512
#define BLOCKS_PER_SLICE 624                 // ceil(19947/32)
#define NSLICES (BB * HD)

__device__ __forceinline__ unsigned jslot(int gl, int s) {
    return (unsigned)(gl * 16 + (s ^ (gl & 7)));   // bijective; conflict-free reads
}

__global__ __launch_bounds__(256, 4) void msda_fwd_pair(
    const _Float16* __restrict__ v16,  // repacked (see layout above)
    const float* __restrict__ loc,
    const float* __restrict__ attw,
    float* __restrict__ out)
{
    __shared__ __align__(8)  u32   s_of[JOBS * 2];
    __shared__ __align__(16) float s_w [JOBS * 4];

    const int Hs[NLV]  = {100, 50, 25, 13};
    const int Ws[NLV]  = {150, 75, 38, 19};
    const int CN0[NLV] = {0, 38, 19, 10};
    const int CN1[NLV] = {0, 38, 20, 10};
    const int OF0[NLV] = {0,  972800, 1459200, 1584000};
    const int OF1[NLV] = {0, 1216000, 1520000, 1600640};

    const int slice = blockIdx.x & 15;   // pins (b,h) to XCD (L2 residency)
    const int blk   = blockIdx.x >> 4;
    const int b = slice >> 3;
    const int h = slice & 7;
    const int t = (int)threadIdx.x;

    // ---------------- Phase 1: 2 jobs/thread -> LDS ----------------
#pragma unroll
    for (int jj = 0; jj < 2; ++jj) {
        const int j  = t + jj * 256;
        const int gl = j >> 4;
        const int s  = j & 15;
        const int l  = s >> 2;
        const int q  = blk * GPB + gl;
        const int qc = min(q, QTOT - 1);
        const size_t og = ((size_t)b * QTOT + qc) * HD + h;

        const f32x2 lxy = __builtin_nontemporal_load((const f32x2*)loc + og * 16 + s);
        float wa = __builtin_nontemporal_load(attw + og * 16 + s);
        if (q >= QTOT) wa = 0.f;

        const int H = Hs[l], W = Ws[l];
        const float x = lxy.x * (float)W - 0.5f;
        const float y = lxy.y * (float)H - 0.5f;
        const float x0f = floorf(x), y0f = floorf(y);
        const float dx = x - x0f,  dy = y - y0f;
        const int x0 = (int)x0f,   y0 = (int)y0f;   // x0 in [-1,W-1], y0 in [-1,H-1]

        // row weights: OOB rows zeroed (row clamp reuses real data);
        // OOB x needs no zeroing -- pad texels hold zeros.
        const float r0w = ((y0 >= 0) ? (1.f - dy) : 0.f) * wa;
        const float r1w = ((y0 + 1 < H) ? dy : 0.f) * wa;
        f32x4 w;
        w.x = r0w * (1.f - dx);  w.y = r0w * dx;
        w.z = r1w * (1.f - dx);  w.w = r1w * dx;

        const int cy0 = max(y0, 0);
        const int cy1 = min(y0 + 1, H - 1);

        u32 off0, off1;
        if (l == 0) {
            const u32 col = (u32)(x0 + 1);           // padded col in [0,150]
            off0 = ((u32)cy0 * 152u + col) * 64u;
            off1 = ((u32)cy1 * 152u + col) * 64u;
        } else {
            const int copy = x0 & 1;                 // (-1)&1 == 1
            const u32 p  = (u32)((x0 + copy) >> 1);
            const u32 cn = (u32)(copy ? CN1[l] : CN0[l]);
            const u32 lo = (u32)(copy ? OF1[l] : OF0[l]);
            off0 = lo + ((u32)cy0 * cn + p) * 128u;
            off1 = lo + ((u32)cy1 * cn + p) * 128u;
        }

        const unsigned sl = jslot(gl, s);
        u32x2 of; of.x = off0; of.y = off1;
        *(u32x2*)&s_of[sl * 2] = of;
        *(f32x4*)&s_w [sl * 4] = w;
    }

    __syncthreads();

    // -------- Phase 2: batched row-pair gathers (8 loads in flight) --------
    const int gl   = t >> 3;             // 0..31
    const int lane = t & 7;              // lanes 0-3: left texel, 4-7: right
    const int lh   = (t >> 2) & 1;
    const int q    = blk * GPB + gl;
    const char* vb = (const char*)v16 + (size_t)slice * SLICE_BYTES + lane * 16;

    float acc[8] = {0.f, 0.f, 0.f, 0.f, 0.f, 0.f, 0.f, 0.f};
#pragma unroll
    for (int sc = 0; sc < 4; ++sc) {
        f16x8 g0[4], g1[4];
        f32x4 w[4];
        // issue 8 independent gathers before any use (all indices static ->
        // arrays live in registers; addresses come from LDS, no cross-chunk
        // deps, so the compiler may hoist next-chunk loads over these FMAs)
#pragma unroll
        for (int si = 0; si < 4; ++si) {
            const unsigned sl = jslot(gl, sc * 4 + si);
            const u32x2 of = *(const u32x2*)&s_of[sl * 2];
            w[si]  = *(const f32x4*)&s_w [sl * 4];
            g0[si] = *(const f16x8*)(vb + of.x);   // row y0 pair (128B/group)
            g1[si] = *(const f16x8*)(vb + of.y);   // row y1 pair
        }
#pragma unroll
        for (int si = 0; si < 4; ++si) {
            const float wr0 = lh ? w[si].y : w[si].x;
            const float wr1 = lh ? w[si].w : w[si].z;
#pragma unroll
            for (int c = 0; c < 8; ++c) {
                acc[c] += (float)g0[si][c] * wr0;
                acc[c] += (float)g1[si][c] * wr1;
            }
        }
    }

    // combine left/right texel halves (lanes l and l^4 hold same channels)
#pragma unroll
    for (int c = 0; c < 8; ++c)
        acc[c] += __shfl_xor(acc[c], 4, 64);

    if (q < QTOT) {
        const size_t og = ((size_t)b * QTOT + q) * HD + h;
        f32x4 v;
        v.x = lh ? acc[4] : acc[0];
        v.y = lh ? acc[5] : acc[1];
        v.z = lh ? acc[6] : acc[2];
        v.w = lh ? acc[7] : acc[3];
        __builtin_nontemporal_store(v, (f32x4*)out + og * 8 + (t & 3) * 2 + lh);
    }
}

// ---------------- fallback: fp32 gathers, if ws too small ----------------
#define FGPB 32
#define FJOBS (FGPB * 16)
__device__ __forceinline__ unsigned fjslot(int gl, int s) {
    return (unsigned)((gl * 16 + (s ^ (gl & 7))) * 4);
}
__global__ __launch_bounds__(256) void msda_fwd_f32(
    const float* __restrict__ value,
    const float* __restrict__ loc,
    const float* __restrict__ attw,
    float* __restrict__ out)
{
    __shared__ __align__(16) u32   s_ofs[FJOBS * 4];
    __shared__ __align__(16) float s_wts[FJOBS * 4];
    const int Hs[NLV] = {100, 50, 25, 13};
    const int Ws[NLV] = {150, 75, 38, 19};
    const int Ss[NLV] = {0, 15000, 18750, 19700};
    const int slice = blockIdx.x & 15;
    const int blk   = blockIdx.x >> 4;
    const int b = slice >> 3, h = slice & 7;
    const int t = (int)threadIdx.x;
#pragma unroll
    for (int jj = 0; jj < 2; ++jj) {
        const int j  = t + jj * 256;
        const int gl = j >> 4, s = j & 15, l = s >> 2;
        const int q  = blk * FGPB + gl;
        const int qc = min(q, QTOT - 1);
        const size_t og = ((size_t)b * QTOT + qc) * HD + h;
        const f32x2 lxy = __builtin_nontemporal_load((const f32x2*)loc + og * 16 + s);
        float wa = __builtin_nontemporal_load(attw + og * 16 + s);
        if (q >= QTOT) wa = 0.f;
        const int H = Hs[l], W = Ws[l];
        const float x = lxy.x * (float)W - 0.5f;
        const float y = lxy.y * (float)H - 0.5f;
        const float x0f = floorf(x), y0f = floorf(y);
        const float dx = x - x0f, dy = y - y0f;
        const int x0 = (int)x0f, y0 = (int)y0f, x1 = x0 + 1, y1 = y0 + 1;
        const bool vx0 = (x0 >= 0) & (x0 < W), vx1 = (x1 >= 0) & (x1 < W);
        const bool vy0 = (y0 >= 0) & (y0 < H), vy1 = (y1 >= 0) & (y1 < H);
        float w00 = (1.f - dy) * (1.f - dx) * wa, w01 = (1.f - dy) * dx * wa;
        float w10 = dy * (1.f - dx) * wa,         w11 = dy * dx * wa;
        w00 = (vy0 & vx0) ? w00 : 0.f; w01 = (vy0 & vx1) ? w01 : 0.f;
        w10 = (vy1 & vx0) ? w10 : 0.f; w11 = (vy1 & vx1) ? w11 : 0.f;
        const int cx0 = min(max(x0, 0), W - 1), cx1 = min(max(x1, 0), W - 1);
        const int cy0 = min(max(y0, 0), H - 1), cy1 = min(max(y1, 0), H - 1);
        const u32 base = (u32)(((b * LTOT + Ss[l]) * HD + h) * CCH) * 4u;
        const u32 r0 = (u32)(cy0 * W), r1 = (u32)(cy1 * W);
        u32 o0 = base + (r0 + (u32)cx0) * (HD * CCH * 4u);
        u32 o1 = base + (r0 + (u32)cx1) * (HD * CCH * 4u);
        u32 o2 = base + (r1 + (u32)cx0) * (HD * CCH * 4u);
        u32 o3 = base + (r1 + (u32)cx1) * (HD * CCH * 4u);
        const unsigned sb = fjslot(gl, s);
        s_ofs[sb + 0] = o0; s_ofs[sb + 1] = o1;
        s_ofs[sb + 2] = o2; s_ofs[sb + 3] = o3;
        f32x4 wts; wts.x = w00; wts.y = w01; wts.z = w10; wts.w = w11;
        *(f32x4*)&s_wts[sb] = wts;
    }
    __syncthreads();
    const int gl = t >> 3, lane = t & 7;
    const int q  = blk * FGPB + gl;
    const char* vb = (const char*)value + lane * 16;
    f32x4 acc = {0.f, 0.f, 0.f, 0.f};
#pragma unroll
    for (int s = 0; s < 16; ++s) {
        const unsigned sb = fjslot(gl, s);
        const f32x4 w = *(const f32x4*)&s_wts[sb];
        acc += (*(const f32x4*)(vb + s_ofs[sb + 0])) * w.x;
        acc += (*(const f32x4*)(vb + s_ofs[sb + 1])) * w.y;
        acc += (*(const f32x4*)(vb + s_ofs[sb + 2])) * w.z;
        acc += (*(const f32x4*)(vb + s_ofs[sb + 3])) * w.w;
    }
    if (q < QTOT) {
        const size_t og = ((size_t)b * QTOT + q) * HD + h;
        __builtin_nontemporal_store(acc, (f32x4*)out + og * 8 + lane);
    }
}

extern "C" void kernel_launch(void* const* d_in, const int* in_sizes, int n_in,
                              void* d_out, int out_size, void* d_ws, size_t ws_size,
                              hipStream_t stream) {
    const float* value = (const float*)d_in[0];
    const float* loc   = (const float*)d_in[3];
    const float* attw  = (const float*)d_in[4];
    float* out = (float*)d_out;

    if (ws_size >= WS_NEED) {
        _Float16* v16 = (_Float16*)d_ws;
        repack_f16<<<(TOTAL_CHUNKS + 255) / 256, 256, 0, stream>>>(value, v16);
        msda_fwd_pair<<<BLOCKS_PER_SLICE * NSLICES, 256, 0, stream>>>(v16, loc, attw, out);
    } else {
        msda_fwd_f32<<<624 * NSLICES, 256, 0, stream>>>(value, loc, attw, out);
    }
}